// Round 5
// baseline (441.915 us; speedup 1.0000x reference)
//
#include <hip/hip_runtime.h>

typedef unsigned short u16;
typedef unsigned int u32;
typedef __attribute__((ext_vector_type(8))) short bf16x8;
typedef __attribute__((ext_vector_type(4))) float f32x4;

#define NN 50000
#define NE 640000

// ---- bf16 helpers (bf16 -> f32 exact: shift<<16; f32 -> bf16 RNE) ----
__device__ __forceinline__ float bfl(u32 u) { return __uint_as_float(u << 16); }
__device__ __forceinline__ float bfh(u32 u) { return __uint_as_float(u & 0xffff0000u); }
__device__ __forceinline__ float bf1(u16 v) { return __uint_as_float(((u32)v) << 16); }
__device__ __forceinline__ u16 f2bf(float f) {
  u32 u = __float_as_uint(f);
  u32 r = (u + 0x7fffu + ((u >> 16) & 1u)) >> 16;
  return (u16)r;
}

// ---------------- dtype probe ----------------
__global__ void probe_kernel(const u16* __restrict__ x, const int* __restrict__ ei,
                             int* __restrict__ flags) {
  __shared__ int s_f32, s_i32;
  if (threadIdx.x == 0) { s_f32 = 0; s_i32 = 0; }
  __syncthreads();
  int lf = 0, li = 0;
  for (int i = threadIdx.x; i < 8192; i += 256) {
    float v = bf1(x[i]);
    if (!(fabsf(v) < 1e8f)) lf = 1;
    if (ei[2 * i + 1] != 0) li = 1;
  }
  if (lf) s_f32 = 1;
  if (li) s_i32 = 1;
  __syncthreads();
  if (threadIdx.x == 0) {
    flags[0] = s_f32;
    flags[1] = s_i32 ? 0 : 1;
  }
}

// ---------------- CSR build ----------------
__device__ __forceinline__ int edge_val(const int* __restrict__ w, long j, int i64) {
  return i64 ? w[2 * j] : w[j];
}

__global__ void count_kernel(const int* __restrict__ ei, const int* __restrict__ flags,
                             int* __restrict__ cnt, int E) {
  int e = blockIdx.x * blockDim.x + threadIdx.x;
  if (e >= E) return;
  int d = edge_val(ei, (long)E + e, flags[1]);
  if ((u32)d < (u32)NN) atomicAdd(&cnt[d], 1);
}

__global__ void scan_local(const int* __restrict__ cnt, int* __restrict__ excl,
                           int* __restrict__ bsum, int n) {
  __shared__ int sd[256];
  int t = threadIdx.x;
  int g = blockIdx.x * 256 + t;
  int v = (g < n) ? cnt[g] : 0;
  sd[t] = v;
  __syncthreads();
  for (int off = 1; off < 256; off <<= 1) {
    int x = (t >= off) ? sd[t - off] : 0;
    __syncthreads();
    sd[t] += x;
    __syncthreads();
  }
  int incl = sd[t];
  if (g < n) excl[g] = incl - v;
  if (t == 255) bsum[blockIdx.x] = incl;
}

__global__ void scan_totals(const int* __restrict__ bsum, int* __restrict__ boff, int nb) {
  __shared__ int sd[256];
  int t = threadIdx.x;
  int v = (t < nb) ? bsum[t] : 0;
  sd[t] = v;
  __syncthreads();
  for (int off = 1; off < 256; off <<= 1) {
    int x = (t >= off) ? sd[t - off] : 0;
    __syncthreads();
    sd[t] += x;
    __syncthreads();
  }
  if (t < nb) boff[t] = sd[t] - v;
}

__global__ void scan_add(const int* __restrict__ excl, const int* __restrict__ boff,
                         const int* __restrict__ cnt, int* __restrict__ rowptr,
                         int* __restrict__ fillp, int n) {
  int g = blockIdx.x * 256 + threadIdx.x;
  if (g < n) {
    int e2 = excl[g] + boff[blockIdx.x];
    rowptr[g] = e2;
    fillp[g] = e2;
    if (g == n - 1) rowptr[n] = e2 + cnt[g];
  }
}

__global__ void fill_kernel(const int* __restrict__ ei, const int* __restrict__ flags,
                            int* __restrict__ fillp, int* __restrict__ col, int E) {
  int e = blockIdx.x * blockDim.x + threadIdx.x;
  if (e >= E) return;
  int i64 = flags[1];
  int s = edge_val(ei, (long)e, i64);
  int d = edge_val(ei, (long)E + e, i64);
  if ((u32)d >= (u32)NN) return;
  int p = atomicAdd(&fillp[d], 1);
  col[p] = ((u32)s < (u32)NN) ? s : 0;
}

// ---------------- weight pre-transpose: Wt[j][k] = W[k][j], output bf16 ----------------
__global__ void transpose_w(const void* W0, const void* W1, const void* W2,
                            const void* W3, const void* W4, const void* W5,
                            u16* T0, u16* T1, u16* T2, u16* T3, u16* T4, u16* T5,
                            const int* __restrict__ flags) {
  int y = blockIdx.y;
  int M = (y < 3) ? 128 : 256;
  int flat = blockIdx.x * 256 + threadIdx.x;
  if (flat >= M * 128) return;
  int j = flat >> 7;
  int k = flat & 127;
  const void* W = (y == 0) ? W0 : (y == 1) ? W1 : (y == 2) ? W2 : (y == 3) ? W3 : (y == 4) ? W4 : W5;
  u16* T = (y == 0) ? T0 : (y == 1) ? T1 : (y == 2) ? T2 : (y == 3) ? T3 : (y == 4) ? T4 : T5;
  u16 v;
  if (flags[0])
    v = f2bf(((const float*)W)[(size_t)k * M + j]);
  else
    v = ((const u16*)W)[(size_t)k * M + j];
  T[(size_t)j * 128 + k] = v;
}

// ---------------- MFMA GEMM (unchanged) ----------------
#define LSTR 136
__global__ __launch_bounds__(256) void gemm3_mfma(
    const void* __restrict__ X,
    const u16* __restrict__ Wta, const u16* __restrict__ Wtb, const u16* __restrict__ Wtc,
    const void* __restrict__ bias,
    u16* __restrict__ Ya, u16* __restrict__ Yb, u16* __restrict__ Yc,
    const int* __restrict__ flags, int x_follows, int N, int M) {
  __shared__ __align__(16) u16 Xs[64 * LSTR];
  __shared__ __align__(16) u16 Bs[128 * LSTR];
  const int K = 128;
  int t = threadIdx.x;
  int lane = t & 63;
  int w = t >> 6;
  int n0g = blockIdx.x * 64;
  int c0 = blockIdx.z * 128;
  int F32X = x_follows ? flags[0] : 0;
  const u16* Wt = (blockIdx.y == 0) ? Wta : ((blockIdx.y == 1) ? Wtb : Wtc);
  u16* Y = (blockIdx.y == 0) ? Ya : ((blockIdx.y == 1) ? Yb : Yc);

  if (!F32X) {
    const u16* Xg = (const u16*)X;
    for (int it = 0; it < 4; ++it) {
      int i = t + 256 * it;
      int r = i >> 4, c8 = (i & 15) * 8;
      int n = n0g + r;
      uint4 v = make_uint4(0, 0, 0, 0);
      if (n < N) v = *(const uint4*)(Xg + (size_t)n * K + c8);
      *(uint4*)(Xs + r * LSTR + c8) = v;
    }
  } else {
    const float* Xg = (const float*)X;
    for (int it = 0; it < 4; ++it) {
      int i = t + 256 * it;
      int r = i >> 4, c8 = (i & 15) * 8;
      int n = n0g + r;
      uint4 pk = make_uint4(0, 0, 0, 0);
      if (n < N) {
        float4 f0 = *(const float4*)(Xg + (size_t)n * K + c8);
        float4 f1 = *(const float4*)(Xg + (size_t)n * K + c8 + 4);
        pk.x = (u32)f2bf(f0.x) | ((u32)f2bf(f0.y) << 16);
        pk.y = (u32)f2bf(f0.z) | ((u32)f2bf(f0.w) << 16);
        pk.z = (u32)f2bf(f1.x) | ((u32)f2bf(f1.y) << 16);
        pk.w = (u32)f2bf(f1.z) | ((u32)f2bf(f1.w) << 16);
      }
      *(uint4*)(Xs + r * LSTR + c8) = pk;
    }
  }
  for (int it = 0; it < 8; ++it) {
    int i = t + 256 * it;
    int j = i >> 4, k8 = (i & 15) * 8;
    uint4 v = *(const uint4*)(Wt + (size_t)(c0 + j) * K + k8);
    *(uint4*)(Bs + j * LSTR + k8) = v;
  }
  __syncthreads();

  int m0 = (w >> 1) * 32;
  int n0 = (w & 1) * 64;
  int l15 = lane & 15;
  int q8 = (lane >> 4) * 8;
  f32x4 acc[2][4];
#pragma unroll
  for (int i = 0; i < 2; ++i)
#pragma unroll
    for (int j = 0; j < 4; ++j) acc[i][j] = (f32x4){0.f, 0.f, 0.f, 0.f};

#pragma unroll
  for (int kc = 0; kc < 4; ++kc) {
    int ko = kc * 32 + q8;
    bf16x8 a[2], b[4];
#pragma unroll
    for (int i = 0; i < 2; ++i)
      a[i] = *(const bf16x8*)(Xs + (m0 + i * 16 + l15) * LSTR + ko);
#pragma unroll
    for (int j = 0; j < 4; ++j)
      b[j] = *(const bf16x8*)(Bs + (n0 + j * 16 + l15) * LSTR + ko);
#pragma unroll
    for (int i = 0; i < 2; ++i)
#pragma unroll
      for (int j = 0; j < 4; ++j)
        acc[i][j] = __builtin_amdgcn_mfma_f32_16x16x32_bf16(a[i], b[j], acc[i][j], 0, 0, 0);
  }
  __syncthreads();

  float bv[4] = {0.f, 0.f, 0.f, 0.f};
  if (blockIdx.y == 2) {
    int F32 = flags[0];
#pragma unroll
    for (int j = 0; j < 4; ++j) {
      int c = c0 + n0 + j * 16 + l15;
      bv[j] = F32 ? ((const float*)bias)[c] : bf1(((const u16*)bias)[c]);
    }
  }

  u16* Ct = Xs;
#pragma unroll
  for (int i = 0; i < 2; ++i)
#pragma unroll
    for (int j = 0; j < 4; ++j) {
      int col = n0 + j * 16 + l15;
      int rbase = m0 + i * 16 + (lane >> 4) * 4;
#pragma unroll
      for (int r = 0; r < 4; ++r)
        Ct[(rbase + r) * LSTR + col] = f2bf(acc[i][j][r] + bv[j]);
    }
  __syncthreads();

  for (int it = 0; it < 4; ++it) {
    int i = t + 256 * it;
    int r = i >> 4, c8 = (i & 15) * 8;
    int n = n0g + r;
    if (n < N) {
      uint4 v = *(const uint4*)(Ct + r * LSTR + c8);
      *(uint4*)(Y + (size_t)n * M + c0 + c8) = v;
    }
  }
}

// ---------------- per-node attention dots: A[n]=att.xl[n], B[n]=att.xr[n] ----------------
template <int F>
__global__ __launch_bounds__(256) void ab_kernel(
    const u16* __restrict__ xl, const u16* __restrict__ xr, const void* __restrict__ att,
    const int* __restrict__ flags, float* __restrict__ A, float* __restrict__ B, int N) {
  constexpr int EPL = F / 64;  // 2 or 4 (u32 pairs: 1 or 2)
  int node = blockIdx.x * 4 + (threadIdx.x >> 6);
  if (node >= N) return;
  int lane = threadIdx.x & 63;
  int base = lane * EPL;
  int F32 = flags[0];
  float attv[EPL];
#pragma unroll
  for (int e = 0; e < EPL; ++e)
    attv[e] = F32 ? ((const float*)att)[base + e] : bf1(((const u16*)att)[base + e]);
  float a = 0.f, b = 0.f;
#pragma unroll
  for (int c = 0; c < EPL / 2; ++c) {
    u32 ul = *(const u32*)(xl + (size_t)node * F + base + 2 * c);
    u32 ur = *(const u32*)(xr + (size_t)node * F + base + 2 * c);
    a = fmaf(attv[2 * c], bfl(ul), a);
    a = fmaf(attv[2 * c + 1], bfh(ul), a);
    b = fmaf(attv[2 * c], bfl(ur), b);
    b = fmaf(attv[2 * c + 1], bfh(ur), b);
  }
#pragma unroll
  for (int off = 1; off <= 32; off <<= 1) {
    a += __shfl_xor(a, off, 64);
    b += __shfl_xor(b, off, 64);
  }
  if (lane == 0) {
    A[node] = a;
    B[node] = b;
  }
}

// ---------------- GATv2 aggregation ----------------
// LPE lanes per edge (LPE*8 == F), EPI = 64/LPE edges per iteration.
// Plain exp (no max subtraction: scores are O(+-12), f32-safe).
// score d = 0.6*(A[src]+B[dst]) + 0.4*sum(att*|xl+xr|)  [LeakyReLU 0.2 exact decomposition]
template <int F, int LPE, bool ELU>
__global__ __launch_bounds__(256) void gat_agg_kernel(
    const u16* __restrict__ xl, const u16* __restrict__ xr, const u16* __restrict__ res,
    const void* __restrict__ att, const float* __restrict__ Aarr, const float* __restrict__ Barr,
    const int* __restrict__ rowptr, const int* __restrict__ col,
    void* __restrict__ out, const int* __restrict__ flags, int out_follows, int N) {
  constexpr int EPI = 64 / LPE;
  static_assert(LPE * 8 == F, "layout");
  int lane = threadIdx.x & 63;
  int sl = lane & (LPE - 1);
  int sub = lane / LPE;
  int node = blockIdx.x * 4 + (threadIdx.x >> 6);
  if (node >= N) return;
  int F32 = flags[0];
  int OF32 = out_follows ? F32 : 0;
  int base = sl * 8;

  float xrv[8], attv[8], acc[8];
#pragma unroll
  for (int c = 0; c < 4; ++c) {
    u32 ur = *(const u32*)(xr + (size_t)node * F + base + 2 * c);
    xrv[2 * c] = bfl(ur);
    xrv[2 * c + 1] = bfh(ur);
  }
#pragma unroll
  for (int e = 0; e < 8; ++e) {
    attv[e] = F32 ? ((const float*)att)[base + e] : bf1(((const u16*)att)[base + e]);
    acc[e] = 0.f;
  }
  float Bv = Barr[node];
  float l = 0.f;
  int beg = rowptr[node], end = rowptr[node + 1];

  for (int cs = beg; cs < end; cs += 64) {
    int n = min(64, end - cs);
    int idxl = cs + lane;
    int myc = (idxl < end) ? col[idxl] : 0;
    float myA = Aarr[myc];
    int itc = (n + EPI - 1) / EPI;

    // 2-deep pipeline
    int c0 = __shfl(myc, sub, 64);
    float a0 = __shfl(myA, sub, 64);
    uint4 v0 = *(const uint4*)(xl + (size_t)c0 * F + base);
    int c1 = __shfl(myc, EPI + sub, 64);
    float a1 = __shfl(myA, EPI + sub, 64);
    uint4 v1 = (itc > 1) ? *(const uint4*)(xl + (size_t)c1 * F + base) : v0;

    auto body = [&](uint4 cur, float aA, int it) {
      float xlv[8];
      xlv[0] = bfl(cur.x); xlv[1] = bfh(cur.x);
      xlv[2] = bfl(cur.y); xlv[3] = bfh(cur.y);
      xlv[4] = bfl(cur.z); xlv[5] = bfh(cur.z);
      xlv[6] = bfl(cur.w); xlv[7] = bfh(cur.w);
      float r = 0.f;
#pragma unroll
      for (int e = 0; e < 8; ++e) {
        float h = xlv[e] + xrv[e];
        r = fmaf(attv[e], fabsf(h), r);
      }
#pragma unroll
      for (int off = 1; off < LPE; off <<= 1) r += __shfl_xor(r, off, 64);
      float d = fmaf(0.4f, r, 0.6f * (aA + Bv));
      int act = (it * EPI + sub) < n;
      float w = act ? __expf(d) : 0.f;
      l += w;
#pragma unroll
      for (int e = 0; e < 8; ++e) acc[e] = fmaf(w, xlv[e], acc[e]);
    };

    int it = 0;
    while (it < itc) {
      body(v0, a0, it);
      if (it + 2 < itc) {
        int j = (it + 2) * EPI + sub;
        int cn = __shfl(myc, j, 64);
        a0 = __shfl(myA, j, 64);
        v0 = *(const uint4*)(xl + (size_t)cn * F + base);
      }
      ++it;
      if (it >= itc) break;
      body(v1, a1, it);
      if (it + 2 < itc) {
        int j = (it + 2) * EPI + sub;
        int cn = __shfl(myc, j, 64);
        a1 = __shfl(myA, j, 64);
        v1 = *(const uint4*)(xl + (size_t)cn * F + base);
      }
      ++it;
    }
  }

  // merge sub-slot partials (disjoint edge subsets, same features)
#pragma unroll
  for (int off = LPE; off < 64; off <<= 1) {
    l += __shfl_xor(l, off, 64);
#pragma unroll
    for (int e = 0; e < 8; ++e) acc[e] += __shfl_xor(acc[e], off, 64);
  }
  float inv = 1.f / (l + 1e-16f);
  if (sub == 0) {
    float ov[8];
#pragma unroll
    for (int e = 0; e < 8; ++e) {
      float o = fmaf(acc[e] , inv, bf1(res[(size_t)node * F + base + e]));
      if (ELU) o = (o > 0.f) ? o : (__expf(o) - 1.f);
      ov[e] = o;
    }
    if (OF32) {
      float* of = (float*)out;
#pragma unroll
      for (int e = 0; e < 8; ++e) of[(size_t)node * F + base + e] = ov[e];
    } else {
      u16* o16 = (u16*)out;
      uint4 pk;
      pk.x = (u32)f2bf(ov[0]) | ((u32)f2bf(ov[1]) << 16);
      pk.y = (u32)f2bf(ov[2]) | ((u32)f2bf(ov[3]) << 16);
      pk.z = (u32)f2bf(ov[4]) | ((u32)f2bf(ov[5]) << 16);
      pk.w = (u32)f2bf(ov[6]) | ((u32)f2bf(ov[7]) << 16);
      *(uint4*)(o16 + (size_t)node * F + base) = pk;
    }
  }
}

extern "C" void kernel_launch(void* const* d_in, const int* in_sizes, int n_in,
                              void* d_out, int out_size, void* d_ws, size_t ws_size,
                              hipStream_t stream) {
  const u16* x16 = (const u16*)d_in[0];
  const int* ei = (const int*)d_in[1];
  const int N = NN, E = NE;

  char* ws = (char*)d_ws;
  size_t off = 0;
  auto alloc = [&](size_t bytes) -> void* {
    void* p = (void*)(ws + off);
    off += (bytes + 255) & ~(size_t)255;
    return p;
  };
  int* flags = (int*)alloc(2 * 4);
  int* cnt = (int*)alloc((size_t)N * 4);
  int* rowptr = (int*)alloc((size_t)(N + 1) * 4);
  int* fillp = (int*)alloc((size_t)N * 4);
  int* colb = (int*)alloc((size_t)E * 4);
  int* excl = (int*)alloc((size_t)N * 4);
  int* bsum = (int*)alloc(256 * 4);
  int* boff = (int*)alloc(256 * 4);
  float* Aarr = (float*)alloc((size_t)N * 4);
  float* Barr = (float*)alloc((size_t)N * 4);
  u16* Wt1a = (u16*)alloc((size_t)128 * 128 * 2);
  u16* Wt1b = (u16*)alloc((size_t)128 * 128 * 2);
  u16* Wt1c = (u16*)alloc((size_t)128 * 128 * 2);
  u16* Wt2a = (u16*)alloc((size_t)256 * 128 * 2);
  u16* Wt2b = (u16*)alloc((size_t)256 * 128 * 2);
  u16* Wt2c = (u16*)alloc((size_t)256 * 128 * 2);
  u16* buf1 = (u16*)alloc((size_t)N * 256 * 2);
  u16* buf2 = (u16*)alloc((size_t)N * 256 * 2);
  u16* buf3 = (u16*)alloc((size_t)N * 256 * 2);
  u16* h1 = (u16*)alloc((size_t)N * 128 * 2);
  (void)ws_size; (void)n_in; (void)in_sizes; (void)out_size;

  int nb = (N + 255) / 256;

  probe_kernel<<<1, 256, 0, stream>>>(x16, ei, flags);
  hipMemsetAsync(cnt, 0, (size_t)N * 4, stream);
  count_kernel<<<(E + 255) / 256, 256, 0, stream>>>(ei, flags, cnt, E);
  scan_local<<<nb, 256, 0, stream>>>(cnt, excl, bsum, N);
  scan_totals<<<1, 256, 0, stream>>>(bsum, boff, nb);
  scan_add<<<nb, 256, 0, stream>>>(excl, boff, cnt, rowptr, fillp, N);
  fill_kernel<<<(E + 255) / 256, 256, 0, stream>>>(ei, flags, fillp, colb, E);
  transpose_w<<<dim3(128, 6), 256, 0, stream>>>(
      d_in[2], d_in[3], d_in[5], d_in[7], d_in[8], d_in[10],
      Wt1a, Wt1b, Wt1c, Wt2a, Wt2b, Wt2c, flags);

  int gx = (N + 63) / 64;
  int gn4 = (N + 3) / 4;
  // Layer 1: 128 -> 128
  gemm3_mfma<<<dim3(gx, 3, 1), 256, 0, stream>>>(
      d_in[0], Wt1a, Wt1b, Wt1c, d_in[6], buf1, buf2, buf3, flags, 1, N, 128);
  ab_kernel<128><<<gn4, 256, 0, stream>>>(buf1, buf2, d_in[4], flags, Aarr, Barr, N);
  gat_agg_kernel<128, 16, true><<<gn4, 256, 0, stream>>>(
      buf1, buf2, buf3, d_in[4], Aarr, Barr, rowptr, colb, h1, flags, 0, N);
  // Layer 2: 128 -> 256
  gemm3_mfma<<<dim3(gx, 3, 2), 256, 0, stream>>>(
      h1, Wt2a, Wt2b, Wt2c, d_in[11], buf1, buf2, buf3, flags, 0, N, 256);
  ab_kernel<256><<<gn4, 256, 0, stream>>>(buf1, buf2, d_in[9], flags, Aarr, Barr, N);
  gat_agg_kernel<256, 32, false><<<gn4, 256, 0, stream>>>(
      buf1, buf2, buf3, d_in[9], Aarr, Barr, rowptr, colb, d_out, flags, 1, N);
}